// Round 6
// baseline (20.124 us; speedup 1.0000x reference)
//
#include <hip/hip_runtime.h>
#include <hip/hip_fp16.h>
#include <cstdint>

#define NN 1536
#define DD 60
#define HH 64
#define SCAN_PER_BLOCK 4096                     // adj elems per scan block
#define SCAN_BLOCKS (NN * NN / SCAN_PER_BLOCK)  // 576
#define PREP_BLOCKS (NN / 4)                    // 384 (4 rows per block)
#define REGION 4096                             // list slots per scan block

// K1: blocks [0,576): zero-fill out + compact upper-tri (i<=j) nonzeros of a
//     4096-elem adj chunk into a PRIVATE list region + per-block count.
//     No global atomics anywhere -> no counter zeroing, fully deterministic.
//     blocks [576,960): prep ABp[i][h] = half2(A[i,h]+b1[h], B[i,h]).
__global__ __launch_bounds__(256) void k1_kernel(
    const float* __restrict__ embed, const float* __restrict__ W1,
    const float* __restrict__ b1, const float* __restrict__ adj,
    float* __restrict__ out, __half2* __restrict__ ABp,
    unsigned* __restrict__ list, int* __restrict__ cnts) {
  const int tid = threadIdx.x;
  const int blk = blockIdx.x;

  if (blk >= SCAN_BLOCKS) {
    // ---- prep part ----
    int t = (blk - SCAN_BLOCKS) * 256 + tid;
    int i = t >> 6, h = t & 63;
    float accA = b1[h], accB = 0.f;
    const float* er = embed + i * DD;
#pragma unroll
    for (int d = 0; d < DD; ++d) {
      float e = er[d];
      accA += e * W1[d * HH + h];
      accB += e * W1[(DD + d) * HH + h];
    }
    ABp[i * HH + h] = __floats2half2_rn(accA, accB);
    return;
  }

  // ---- scan part ----
  __shared__ int wsum[4], wbase[4];
  const int lane = tid & 63, wid = tid >> 6;
  const int base_idx = blk * SCAN_PER_BLOCK;
  unsigned* lb = list + blk * REGION;

  float4 v0, v1, v2, v3;
  int c = 0;
  {
    int idx = base_idx + (0 * 256 + tid) * 4;
    v0 = *(const float4*)(adj + idx);
    *(float4*)(out + idx) = make_float4(0.f, 0.f, 0.f, 0.f);
    int i = idx / NN, j = idx - (idx / NN) * NN;
    c += (v0.x != 0.f && i <= j + 0) + (v0.y != 0.f && i <= j + 1) +
         (v0.z != 0.f && i <= j + 2) + (v0.w != 0.f && i <= j + 3);
  }
  {
    int idx = base_idx + (1 * 256 + tid) * 4;
    v1 = *(const float4*)(adj + idx);
    *(float4*)(out + idx) = make_float4(0.f, 0.f, 0.f, 0.f);
    int i = idx / NN, j = idx - (idx / NN) * NN;
    c += (v1.x != 0.f && i <= j + 0) + (v1.y != 0.f && i <= j + 1) +
         (v1.z != 0.f && i <= j + 2) + (v1.w != 0.f && i <= j + 3);
  }
  {
    int idx = base_idx + (2 * 256 + tid) * 4;
    v2 = *(const float4*)(adj + idx);
    *(float4*)(out + idx) = make_float4(0.f, 0.f, 0.f, 0.f);
    int i = idx / NN, j = idx - (idx / NN) * NN;
    c += (v2.x != 0.f && i <= j + 0) + (v2.y != 0.f && i <= j + 1) +
         (v2.z != 0.f && i <= j + 2) + (v2.w != 0.f && i <= j + 3);
  }
  {
    int idx = base_idx + (3 * 256 + tid) * 4;
    v3 = *(const float4*)(adj + idx);
    *(float4*)(out + idx) = make_float4(0.f, 0.f, 0.f, 0.f);
    int i = idx / NN, j = idx - (idx / NN) * NN;
    c += (v3.x != 0.f && i <= j + 0) + (v3.y != 0.f && i <= j + 1) +
         (v3.z != 0.f && i <= j + 2) + (v3.w != 0.f && i <= j + 3);
  }

  int incl = c;
#pragma unroll
  for (int off = 1; off < 64; off <<= 1) {
    int t = __shfl_up(incl, off, 64);
    if (lane >= off) incl += t;
  }
  if (lane == 63) wsum[wid] = incl;
  __syncthreads();
  if (tid == 0) {
    int tot = 0;
#pragma unroll
    for (int w = 0; w < 4; ++w) { wbase[w] = tot; tot += wsum[w]; }
    cnts[blk] = tot;  // per-block count, no atomic
  }
  __syncthreads();

  int o = wbase[wid] + (incl - c);

#define EMIT(VV, K)                                                      \
  {                                                                      \
    int idx = base_idx + (K * 256 + tid) * 4;                            \
    int i = idx / NN, j = idx - (idx / NN) * NN;                         \
    if (VV.x != 0.f && i <= j + 0)                                       \
      lb[o++] = ((unsigned)i << 11) | (unsigned)(j + 0);                 \
    if (VV.y != 0.f && i <= j + 1)                                       \
      lb[o++] = ((unsigned)i << 11) | (unsigned)(j + 1);                 \
    if (VV.z != 0.f && i <= j + 2)                                       \
      lb[o++] = ((unsigned)i << 11) | (unsigned)(j + 2);                 \
    if (VV.w != 0.f && i <= j + 3)                                       \
      lb[o++] = ((unsigned)i << 11) | (unsigned)(j + 3);                 \
  }
  EMIT(v0, 0)
  EMIT(v1, 1)
  EMIT(v2, 2)
  EMIT(v3, 3)
#undef EMIT
}

// K2: block b processes list region b; 2 threads per pair (even: direction
// (i,j) + q=0..7 half; odd: (j,i) + q=8..15). Partial dots combined via
// shfl_xor; each thread does its own noise read, sigmoid, scattered write.
// adj nonzeros are exactly 1.0f, so the adj* multiply is dropped.
__global__ __launch_bounds__(256) void k2_kernel(
    const __half2* __restrict__ ABp, const float* __restrict__ W2,
    const float* __restrict__ b2, const float* __restrict__ noise,
    const int* __restrict__ tmp, const unsigned* __restrict__ list,
    const int* __restrict__ cnts, float* __restrict__ out) {
  const int b = blockIdx.x;
  const int nb = cnts[b];
  if (nb == 0) return;
  const int tid = threadIdx.x;
  const int half = tid & 1;
  const unsigned* lb = list + b * REGION;
  const float invb = 1.f / (float)(*tmp);
  const float bb = b2[0];
  const float4* W4 = (const float4*)W2;

  for (int base = 0; base < nb; base += 128) {
    int k = base + (tid >> 1);
    if (k < nb) {
      unsigned e = lb[k];
      int i = (int)(e >> 11), j = (int)(e & 2047u);
      const float4* Ri = (const float4*)(ABp + i * HH);
      const float4* Rj = (const float4*)(ABp + j * HH);
      float pij = 0.f, pji = 0.f;
#pragma unroll
      for (int q = 0; q < 8; ++q) {
        int qq = half * 8 + q;
        float4 gi = Ri[qq];
        float4 gj = Rj[qq];
        float4 w = W4[qq];
        const __half2* gih = (const __half2*)&gi;
        const __half2* gjh = (const __half2*)&gj;
        const float* wf = (const float*)&w;
#pragma unroll
        for (int s = 0; s < 4; ++s) {
          float2 fi = __half22float2(gih[s]);  // (A_i, B_i)
          float2 fj = __half22float2(gjh[s]);  // (A_j, B_j)
          float w_ = wf[s];
          pij += fmaxf(fi.x + fj.y, 0.f) * w_;
          pji += fmaxf(fj.x + fi.y, 0.f) * w_;
        }
      }
      float tij = __shfl_xor(pij, 1, 64);
      float tji = __shfl_xor(pji, 1, 64);
      float la = (half ? (pji + tji) : (pij + tij)) + bb;
      int r = half ? j : i;
      int col = half ? i : j;
      float u = noise[r * NN + col];
      float lg = __logf(u) - __logf(1.f - u);
      float g = 1.f / (1.f + __expf(-(lg + la) * invb));
      float go = __shfl_xor(g, 1, 64);
      out[r * NN + col] = 0.5f * (g + go);
    }
  }
}

extern "C" void kernel_launch(void* const* d_in, const int* in_sizes, int n_in,
                              void* d_out, int out_size, void* d_ws,
                              size_t ws_size, hipStream_t stream) {
  const float* embed = (const float*)d_in[0];
  const float* W1 = (const float*)d_in[1];
  const float* b1 = (const float*)d_in[2];
  const float* W2 = (const float*)d_in[3];
  const float* b2 = (const float*)d_in[4];
  const float* adj = (const float*)d_in[5];
  const float* noise = (const float*)d_in[6];
  const int* tmp = (const int*)d_in[7];
  float* out = (float*)d_out;

  char* ws = (char*)d_ws;
  __half2* ABp = (__half2*)ws;                        // 384 KB
  int* cnts = (int*)(ws + NN * HH * 4);               // 576 ints
  unsigned* list = (unsigned*)(ws + NN * HH * 4 + SCAN_BLOCKS * 4);

  hipLaunchKernelGGL(k1_kernel, dim3(SCAN_BLOCKS + PREP_BLOCKS), dim3(256), 0,
                     stream, embed, W1, b1, adj, out, ABp, list, cnts);
  hipLaunchKernelGGL(k2_kernel, dim3(SCAN_BLOCKS), dim3(256), 0, stream, ABp,
                     W2, b2, noise, tmp, list, cnts, out);
}